// Round 1
// baseline (273.095 us; speedup 1.0000x reference)
//
#include <hip/hip_runtime.h>
#include <math.h>

#define C_DIM 256
#define H_DIM 128
#define W_DIM 128
#define B_DIM 4
#define HW (H_DIM*W_DIM)
#define N_ROIS 512
#define OH 7
#define OW 7
#define TOKENS (N_ROIS*OH*OW)   // 25088
#define SPS 0.0625f             // spatial scale
#define GAMMA 0.1f
#define SCALE 0.0625f           // d^-0.5 = 1/16

// ---------------- precompute 1: A_k = Wk@W_proj, A_v = Wv@W_proj,
//                  Qhat = queries@Wq.T + bq, cv = Wv@b_proj + bv ----------------
__global__ void precompute1(const float* __restrict__ w_proj,
                            const float* __restrict__ in_proj_w,
                            const float* __restrict__ in_proj_b,
                            const float* __restrict__ queries,
                            const float* __restrict__ b_proj,
                            float* __restrict__ A_k, float* __restrict__ A_v,
                            float* __restrict__ Qhat, float* __restrict__ cv) {
    int idx = blockIdx.x * 256 + threadIdx.x;
    if (idx < 65536) {                       // A_k[i,j]
        int i = idx >> 8, j = idx & 255;
        const float* wk = in_proj_w + (size_t)(256 + i) * 256;
        float s = 0.f;
        for (int t = 0; t < 256; t++) s += wk[t] * w_proj[t * 256 + j];
        A_k[idx] = s;
    } else if (idx < 131072) {               // A_v[i,j]
        int e = idx - 65536;
        int i = e >> 8, j = e & 255;
        const float* wv = in_proj_w + (size_t)(512 + i) * 256;
        float s = 0.f;
        for (int t = 0; t < 256; t++) s += wv[t] * w_proj[t * 256 + j];
        A_v[e] = s;
    } else if (idx < 143616) {               // Qhat[s,i]
        int e = idx - 131072;
        int s_ = e >> 8, i = e & 255;
        const float* q  = queries + (size_t)s_ * 256;
        const float* wq = in_proj_w + (size_t)i * 256;
        float s = in_proj_b[i];
        for (int t = 0; t < 256; t++) s += q[t] * wq[t];
        Qhat[e] = s;
    } else {                                 // cv[i]
        int i = idx - 143616;
        const float* wv = in_proj_w + (size_t)(512 + i) * 256;
        float s = in_proj_b[512 + i];
        for (int t = 0; t < 256; t++) s += wv[t] * b_proj[t];
        cv[i] = s;
    }
}

// ---------------- precompute 2: u = Qhat@A_k, Mtp = packed(W_o@A_v)^T,
//                  c_out = W_o@cv + b_o ----------------
// Mtp layout: Mtp[((d>>2)*256 + c)*4 + (d&3)] = M[c,d], so a float4 at
// index (d4*256 + c) holds M[c, 4*d4 .. 4*d4+3].
__global__ void precompute2(const float* __restrict__ Qhat,
                            const float* __restrict__ A_k,
                            const float* __restrict__ A_v,
                            const float* __restrict__ out_proj_w,
                            const float* __restrict__ out_proj_b,
                            const float* __restrict__ cv,
                            float* __restrict__ u, float* __restrict__ Mtp,
                            float* __restrict__ c_out) {
    int idx = blockIdx.x * 256 + threadIdx.x;
    if (idx < 12544) {                       // u[s,j]
        int s_ = idx >> 8, j = idx & 255;
        const float* qh = Qhat + (size_t)s_ * 256;
        float s = 0.f;
        for (int i = 0; i < 256; i++) s += qh[i] * A_k[i * 256 + j];
        u[idx] = s;
    } else if (idx < 78080) {                // M[c,d], lanes vary d -> A_v coalesced
        int e = idx - 12544;
        int c = e >> 8, d = e & 255;
        const float* wo = out_proj_w + (size_t)c * 256;
        float s = 0.f;
        for (int i = 0; i < 256; i++) s += wo[i] * A_v[i * 256 + d];
        Mtp[((size_t)(d >> 2) * 256 + c) * 4 + (d & 3)] = s;
    } else {                                 // c_out[c]
        int c = idx - 78080;
        const float* wo = out_proj_w + (size_t)c * 256;
        float s = out_proj_b[c];
        for (int i = 0; i < 256; i++) s += wo[i] * cv[i];
        c_out[c] = s;
    }
}

// ---------------- NCHW -> NHWC transpose of features ----------------
__global__ void transpose_nchw_nhwc(const float* __restrict__ f,
                                    float* __restrict__ ft) {
    __shared__ float tile[64][65];
    int b  = blockIdx.z;
    int c0 = blockIdx.y * 64;
    int s0 = blockIdx.x * 64;
    const float* fin = f + (size_t)b * C_DIM * HW;
    int sl = threadIdx.x & 63, cw = threadIdx.x >> 6;
    #pragma unroll
    for (int k = 0; k < 16; k++) {
        int cl = cw + k * 4;
        tile[cl][sl] = fin[(size_t)(c0 + cl) * HW + s0 + sl];
    }
    __syncthreads();
    float* fo = ft + (size_t)b * HW * C_DIM;
    int cl = threadIdx.x & 63, sw = threadIdx.x >> 6;
    #pragma unroll
    for (int k = 0; k < 16; k++) {
        int sl2 = sw + k * 4;
        fo[(size_t)(s0 + sl2) * C_DIM + c0 + cl] = tile[cl][sl2];
    }
}

// ---------------- fused sample + score + softmax + weighted-mix ----------------
// One wave per token, lane handles 4 channels (float4 on NHWC features).
__global__ void sample_nhwc(const float* __restrict__ feat_t,
                            const float* __restrict__ rois,
                            const float* __restrict__ offs,
                            const float* __restrict__ u,
                            float* __restrict__ m_out) {
    int wave = threadIdx.x >> 6;
    int lane = threadIdx.x & 63;
    int token = blockIdx.x * 4 + wave;
    int n = token / 49;
    int t = token - n * 49;
    int h = t / 7;
    int w = t - h * 7;

    const float* r = rois + (size_t)n * 5;
    int bi   = (int)r[0];
    float x1 = r[1] * SPS - 0.5f;
    float y1 = r[2] * SPS - 0.5f;
    float rw = r[3] * SPS - 0.5f - x1;
    float rh = r[4] * SPS - 0.5f - y1;
    float bw = rw * (1.0f / 7.0f);
    float bh = rh * (1.0f / 7.0f);

    const float* fb = feat_t + (size_t)bi * HW * C_DIM;
    int c4 = lane * 4;
    float4 uv = *(const float4*)(u + (size_t)t * 256 + c4);

    float4 sv[4];
    float  part[4];
    #pragma unroll
    for (int p = 0; p < 4; p++) {
        float offw = offs[((p * 7 + h) * 7 + w) * 2 + 0];
        float offh = offs[((p * 7 + h) * 7 + w) * 2 + 1];
        float y = y1 + ((float)h + 0.5f) * bh + GAMMA * rh * offh;
        float x = x1 + ((float)w + 0.5f) * bw + GAMMA * rw * offw;
        bool valid = (y > -1.0f) && (y < (float)H_DIM) && (x > -1.0f) && (x < (float)W_DIM);
        float yc = fminf(fmaxf(y, 0.f), 127.f);
        float xc = fminf(fmaxf(x, 0.f), 127.f);
        int y0i = (int)floorf(yc);
        int x0i = (int)floorf(xc);
        int y1i = min(y0i + 1, 127);
        int x1i = min(x0i + 1, 127);
        float ly = yc - (float)y0i, lx = xc - (float)x0i;
        float hy = 1.f - ly, hx = 1.f - lx;
        float4 v00 = *(const float4*)(fb + (size_t)(y0i * W_DIM + x0i) * C_DIM + c4);
        float4 v01 = *(const float4*)(fb + (size_t)(y0i * W_DIM + x1i) * C_DIM + c4);
        float4 v10 = *(const float4*)(fb + (size_t)(y1i * W_DIM + x0i) * C_DIM + c4);
        float4 v11 = *(const float4*)(fb + (size_t)(y1i * W_DIM + x1i) * C_DIM + c4);
        float w00 = hy * hx, w01 = hy * lx, w10 = ly * hx, w11 = ly * lx;
        float4 v;
        v.x = w00 * v00.x + w01 * v01.x + w10 * v10.x + w11 * v11.x;
        v.y = w00 * v00.y + w01 * v01.y + w10 * v10.y + w11 * v11.y;
        v.z = w00 * v00.z + w01 * v01.z + w10 * v10.z + w11 * v11.z;
        v.w = w00 * v00.w + w01 * v01.w + w10 * v10.w + w11 * v11.w;
        if (!valid) { v.x = 0.f; v.y = 0.f; v.z = 0.f; v.w = 0.f; }
        sv[p] = v;
        part[p] = uv.x * v.x + uv.y * v.y + uv.z * v.z + uv.w * v.w;
    }
    // wave-wide reduction (butterfly) -> every lane holds the 4 dot products
    #pragma unroll
    for (int mbit = 1; mbit < 64; mbit <<= 1) {
        #pragma unroll
        for (int p = 0; p < 4; p++) part[p] += __shfl_xor(part[p], mbit, 64);
    }
    float sc0 = part[0] * SCALE, sc1 = part[1] * SCALE;
    float sc2 = part[2] * SCALE, sc3 = part[3] * SCALE;
    float mx = fmaxf(fmaxf(sc0, sc1), fmaxf(sc2, sc3));
    float e0 = __expf(sc0 - mx), e1 = __expf(sc1 - mx);
    float e2 = __expf(sc2 - mx), e3 = __expf(sc3 - mx);
    float inv = 1.f / (e0 + e1 + e2 + e3);
    float4 m;
    m.x = (e0 * sv[0].x + e1 * sv[1].x + e2 * sv[2].x + e3 * sv[3].x) * inv;
    m.y = (e0 * sv[0].y + e1 * sv[1].y + e2 * sv[2].y + e3 * sv[3].y) * inv;
    m.z = (e0 * sv[0].z + e1 * sv[1].z + e2 * sv[2].z + e3 * sv[3].z) * inv;
    m.w = (e0 * sv[0].w + e1 * sv[1].w + e2 * sv[2].w + e3 * sv[3].w) * inv;
    *(float4*)(m_out + (size_t)token * 256 + c4) = m;
}

// ---------------- fallback sampler (NCHW, scalar, only if ws too small) ----------------
__global__ void sample_generic(const float* __restrict__ feat,
                               const float* __restrict__ rois,
                               const float* __restrict__ offs,
                               const float* __restrict__ u,
                               float* __restrict__ m_out,
                               int ch_stride, int pix_stride) {
    __shared__ float red[4][4];
    int token = blockIdx.x;
    int n = token / 49;
    int t = token - n * 49;
    int h = t / 7;
    int w = t - h * 7;
    const float* r = rois + (size_t)n * 5;
    int bi   = (int)r[0];
    float x1 = r[1] * SPS - 0.5f;
    float y1 = r[2] * SPS - 0.5f;
    float rw = r[3] * SPS - 0.5f - x1;
    float rh = r[4] * SPS - 0.5f - y1;
    float bw = rw * (1.0f / 7.0f);
    float bh = rh * (1.0f / 7.0f);
    int c = threadIdx.x;
    const float* fb = feat + (size_t)bi * HW * C_DIM;
    float u_c = u[(size_t)t * 256 + c];
    float sv[4], part[4];
    #pragma unroll
    for (int p = 0; p < 4; p++) {
        float offw = offs[((p * 7 + h) * 7 + w) * 2 + 0];
        float offh = offs[((p * 7 + h) * 7 + w) * 2 + 1];
        float y = y1 + ((float)h + 0.5f) * bh + GAMMA * rh * offh;
        float x = x1 + ((float)w + 0.5f) * bw + GAMMA * rw * offw;
        bool valid = (y > -1.0f) && (y < (float)H_DIM) && (x > -1.0f) && (x < (float)W_DIM);
        float yc = fminf(fmaxf(y, 0.f), 127.f);
        float xc = fminf(fmaxf(x, 0.f), 127.f);
        int y0i = (int)floorf(yc);
        int x0i = (int)floorf(xc);
        int y1i = min(y0i + 1, 127);
        int x1i = min(x0i + 1, 127);
        float ly = yc - (float)y0i, lx = xc - (float)x0i;
        float hy = 1.f - ly, hx = 1.f - lx;
        float v00 = fb[(size_t)(y0i * W_DIM + x0i) * pix_stride + (size_t)c * ch_stride];
        float v01 = fb[(size_t)(y0i * W_DIM + x1i) * pix_stride + (size_t)c * ch_stride];
        float v10 = fb[(size_t)(y1i * W_DIM + x0i) * pix_stride + (size_t)c * ch_stride];
        float v11 = fb[(size_t)(y1i * W_DIM + x1i) * pix_stride + (size_t)c * ch_stride];
        float v = hy * hx * v00 + hy * lx * v01 + ly * hx * v10 + ly * lx * v11;
        v = valid ? v : 0.f;
        sv[p] = v;
        part[p] = u_c * v;
    }
    #pragma unroll
    for (int o = 32; o >= 1; o >>= 1) {
        #pragma unroll
        for (int p = 0; p < 4; p++) part[p] += __shfl_down(part[p], o, 64);
    }
    int wv = threadIdx.x >> 6, lane = threadIdx.x & 63;
    if (lane == 0) {
        red[wv][0] = part[0]; red[wv][1] = part[1];
        red[wv][2] = part[2]; red[wv][3] = part[3];
    }
    __syncthreads();
    float sc0 = (red[0][0] + red[1][0] + red[2][0] + red[3][0]) * SCALE;
    float sc1 = (red[0][1] + red[1][1] + red[2][1] + red[3][1]) * SCALE;
    float sc2 = (red[0][2] + red[1][2] + red[2][2] + red[3][2]) * SCALE;
    float sc3 = (red[0][3] + red[1][3] + red[2][3] + red[3][3]) * SCALE;
    float mx = fmaxf(fmaxf(sc0, sc1), fmaxf(sc2, sc3));
    float e0 = __expf(sc0 - mx), e1 = __expf(sc1 - mx);
    float e2 = __expf(sc2 - mx), e3 = __expf(sc3 - mx);
    float inv = 1.f / (e0 + e1 + e2 + e3);
    m_out[(size_t)token * 256 + c] =
        (e0 * sv[0] + e1 * sv[1] + e2 * sv[2] + e3 * sv[3]) * inv;
}

// ---------------- per-roi GEMM: out[n,c,t] = sum_d M[c,d]*m[n,t,d] + c_out[c] ----------------
// m may alias out: all reads happen before the first barrier, writes after.
__global__ void __launch_bounds__(256) roi_gemm(const float* __restrict__ m,
                                                const float* __restrict__ Mtp,
                                                const float* __restrict__ c_out,
                                                float* __restrict__ out) {
    __shared__ float mlds[49 * 260];   // 260 pad: 16B-aligned rows, conflict-free
    int c = threadIdx.x;
    int n = blockIdx.x;
    const float* mb = m + (size_t)n * 12544;
    for (int t = 0; t < 49; t++) mlds[t * 260 + c] = mb[t * 256 + c];
    __syncthreads();
    float acc[49];
    #pragma unroll
    for (int t = 0; t < 49; t++) acc[t] = 0.f;
    const float4* Mp = (const float4*)Mtp;
    for (int d4 = 0; d4 < 64; d4++) {
        float4 w4 = Mp[(size_t)d4 * 256 + c];
        #pragma unroll
        for (int t = 0; t < 49; t++) {
            float4 mv = *(const float4*)&mlds[t * 260 + d4 * 4];
            acc[t] = fmaf(w4.x, mv.x, acc[t]);
            acc[t] = fmaf(w4.y, mv.y, acc[t]);
            acc[t] = fmaf(w4.z, mv.z, acc[t]);
            acc[t] = fmaf(w4.w, mv.w, acc[t]);
        }
    }
    float bias = c_out[c];
    __syncthreads();
    #pragma unroll
    for (int t = 0; t < 49; t++) mlds[t * 260 + c] = acc[t] + bias;
    __syncthreads();
    float* ob = out + (size_t)n * 12544;
    for (int k = 0; k < 49; k++) {
        int flat = k * 256 + c;          // 0..12543  == c2*49 + t2
        int c2 = flat / 49;
        int t2 = flat - c2 * 49;
        ob[flat] = mlds[t2 * 260 + c2];  // coalesced global store
    }
}

extern "C" void kernel_launch(void* const* d_in, const int* in_sizes, int n_in,
                              void* d_out, int out_size, void* d_ws, size_t ws_size,
                              hipStream_t stream) {
    (void)in_sizes; (void)n_in; (void)out_size;
    const float* features   = (const float*)d_in[0];
    const float* rois       = (const float*)d_in[1];
    const float* offs       = (const float*)d_in[2];
    const float* queries    = (const float*)d_in[3];
    const float* w_proj     = (const float*)d_in[4];
    const float* b_proj     = (const float*)d_in[5];
    const float* in_proj_w  = (const float*)d_in[6];
    const float* in_proj_b  = (const float*)d_in[7];
    const float* out_proj_w = (const float*)d_in[8];
    const float* out_proj_b = (const float*)d_in[9];
    float* out = (float*)d_out;
    float* ws  = (float*)d_ws;

    float* A_k    = ws;                 // 65536
    float* A_v    = A_k  + 65536;       // 65536
    float* Qhat   = A_v  + 65536;       // 12544
    float* cv     = Qhat + 12544;       // 256
    float* u      = cv   + 256;         // 12544
    float* Mtp    = u    + 12544;       // 65536 (16B aligned: offset 156416 floats)
    float* c_out  = Mtp  + 65536;       // 256
    float* feat_t = c_out + 256;        // 16777216

    size_t need = ((size_t)222208 + (size_t)16777216) * 4;
    bool useT = ws_size >= need;

    precompute1<<<562, 256, 0, stream>>>(w_proj, in_proj_w, in_proj_b,
                                         queries, b_proj, A_k, A_v, Qhat, cv);
    precompute2<<<306, 256, 0, stream>>>(Qhat, A_k, A_v, out_proj_w, out_proj_b,
                                         cv, u, Mtp, c_out);

    float* m = out;   // alias: roi_gemm reads its slice fully before writing it
    if (useT) {
        transpose_nchw_nhwc<<<dim3(256, 4, 4), 256, 0, stream>>>(features, feat_t);
        sample_nhwc<<<TOKENS / 4, 256, 0, stream>>>(feat_t, rois, offs, u, m);
    } else {
        sample_generic<<<TOKENS, 256, 0, stream>>>(features, rois, offs, u, m, HW, 1);
    }
    roi_gemm<<<512, 256, 0, stream>>>(m, Mtp, c_out, out);
}

// Round 2
// 203.192 us; speedup vs baseline: 1.3440x; 1.3440x over previous
//
#include <hip/hip_runtime.h>
#include <math.h>

#define C_DIM 256
#define H_DIM 128
#define W_DIM 128
#define B_DIM 4
#define HW (H_DIM*W_DIM)
#define N_ROIS 512
#define OH 7
#define OW 7
#define TOKENS (N_ROIS*OH*OW)   // 25088
#define SPS 0.0625f             // spatial scale
#define GAMMA 0.1f
#define SCALE 0.0625f           // d^-0.5 = 1/16

typedef __attribute__((ext_vector_type(8))) short bf16x8;
typedef __attribute__((ext_vector_type(4))) float f32x4;
typedef __attribute__((ext_vector_type(4))) unsigned short us4;

__device__ inline unsigned short f2bf_rne(float f) {
    unsigned int b = __float_as_uint(f);
    b += 0x7fffu + ((b >> 16) & 1u);
    return (unsigned short)(b >> 16);
}

// ---------------- precompute 1: A_k = Wk@W_proj, A_v = Wv@W_proj,
//                  Qhat = queries@Wq.T + bq, cv = Wv@b_proj + bv ----------------
__global__ void precompute1(const float* __restrict__ w_proj,
                            const float* __restrict__ in_proj_w,
                            const float* __restrict__ in_proj_b,
                            const float* __restrict__ queries,
                            const float* __restrict__ b_proj,
                            float* __restrict__ A_k, float* __restrict__ A_v,
                            float* __restrict__ Qhat, float* __restrict__ cv) {
    int idx = blockIdx.x * 256 + threadIdx.x;
    if (idx < 65536) {                       // A_k[i,j]
        int i = idx >> 8, j = idx & 255;
        const float* wk = in_proj_w + (size_t)(256 + i) * 256;
        float s = 0.f;
        for (int t = 0; t < 256; t++) s += wk[t] * w_proj[t * 256 + j];
        A_k[idx] = s;
    } else if (idx < 131072) {               // A_v[i,j]
        int e = idx - 65536;
        int i = e >> 8, j = e & 255;
        const float* wv = in_proj_w + (size_t)(512 + i) * 256;
        float s = 0.f;
        for (int t = 0; t < 256; t++) s += wv[t] * w_proj[t * 256 + j];
        A_v[e] = s;
    } else if (idx < 143616) {               // Qhat[s,i]
        int e = idx - 131072;
        int s_ = e >> 8, i = e & 255;
        const float* q  = queries + (size_t)s_ * 256;
        const float* wq = in_proj_w + (size_t)i * 256;
        float s = in_proj_b[i];
        for (int t = 0; t < 256; t++) s += q[t] * wq[t];
        Qhat[e] = s;
    } else {                                 // cv[i]
        int i = idx - 143616;
        const float* wv = in_proj_w + (size_t)(512 + i) * 256;
        float s = in_proj_b[512 + i];
        for (int t = 0; t < 256; t++) s += wv[t] * b_proj[t];
        cv[i] = s;
    }
}

// ---------------- precompute 2: u = Qhat@A_k, M = W_o@A_v (as bf16 hi/lo,
//                  natural [c][d] layout = MFMA B-fragment friendly),
//                  optionally fp32 packed Mtp for the fallback path,
//                  c_out = W_o@cv + b_o ----------------
__global__ void precompute2(const float* __restrict__ Qhat,
                            const float* __restrict__ A_k,
                            const float* __restrict__ A_v,
                            const float* __restrict__ out_proj_w,
                            const float* __restrict__ out_proj_b,
                            const float* __restrict__ cv,
                            float* __restrict__ u,
                            unsigned short* __restrict__ Mh,
                            unsigned short* __restrict__ Ml,
                            float* __restrict__ Mtp, int writeMtp,
                            float* __restrict__ c_out) {
    int idx = blockIdx.x * 256 + threadIdx.x;
    if (idx < 12544) {                       // u[s,j]
        int s_ = idx >> 8, j = idx & 255;
        const float* qh = Qhat + (size_t)s_ * 256;
        float s = 0.f;
        for (int i = 0; i < 256; i++) s += qh[i] * A_k[i * 256 + j];
        u[idx] = s;
    } else if (idx < 78080) {                // M[c,d], lanes vary d -> coalesced
        int e = idx - 12544;
        int c = e >> 8, d = e & 255;
        const float* wo = out_proj_w + (size_t)c * 256;
        float s = 0.f;
        for (int i = 0; i < 256; i++) s += wo[i] * A_v[i * 256 + d];
        unsigned short hi = f2bf_rne(s);
        float fh = __uint_as_float(((unsigned int)hi) << 16);
        unsigned short lo = f2bf_rne(s - fh);
        Mh[(size_t)c * 256 + d] = hi;
        Ml[(size_t)c * 256 + d] = lo;
        if (writeMtp)
            Mtp[((size_t)(d >> 2) * 256 + c) * 4 + (d & 3)] = s;
    } else {                                 // c_out[c]
        int c = idx - 78080;
        const float* wo = out_proj_w + (size_t)c * 256;
        float s = out_proj_b[c];
        for (int i = 0; i < 256; i++) s += wo[i] * cv[i];
        c_out[c] = s;
    }
}

// ---------------- NCHW -> NHWC transpose of features ----------------
__global__ void transpose_nchw_nhwc(const float* __restrict__ f,
                                    float* __restrict__ ft) {
    __shared__ float tile[64][65];
    int b  = blockIdx.z;
    int c0 = blockIdx.y * 64;
    int s0 = blockIdx.x * 64;
    const float* fin = f + (size_t)b * C_DIM * HW;
    int sl = threadIdx.x & 63, cw = threadIdx.x >> 6;
    #pragma unroll
    for (int k = 0; k < 16; k++) {
        int cl = cw + k * 4;
        tile[cl][sl] = fin[(size_t)(c0 + cl) * HW + s0 + sl];
    }
    __syncthreads();
    float* fo = ft + (size_t)b * HW * C_DIM;
    int cl = threadIdx.x & 63, sw = threadIdx.x >> 6;
    #pragma unroll
    for (int k = 0; k < 16; k++) {
        int sl2 = sw + k * 4;
        fo[(size_t)(s0 + sl2) * C_DIM + c0 + cl] = tile[cl][sl2];
    }
}

// ---------------- fused sample + score + softmax + weighted-mix ----------------
// One wave per token, lane handles 4 channels (float4 on NHWC features).
__global__ void sample_nhwc(const float* __restrict__ feat_t,
                            const float* __restrict__ rois,
                            const float* __restrict__ offs,
                            const float* __restrict__ u,
                            float* __restrict__ m_out) {
    int wave = threadIdx.x >> 6;
    int lane = threadIdx.x & 63;
    int token = blockIdx.x * 4 + wave;
    int n = token / 49;
    int t = token - n * 49;
    int h = t / 7;
    int w = t - h * 7;

    const float* r = rois + (size_t)n * 5;
    int bi   = (int)r[0];
    float x1 = r[1] * SPS - 0.5f;
    float y1 = r[2] * SPS - 0.5f;
    float rw = r[3] * SPS - 0.5f - x1;
    float rh = r[4] * SPS - 0.5f - y1;
    float bw = rw * (1.0f / 7.0f);
    float bh = rh * (1.0f / 7.0f);

    const float* fb = feat_t + (size_t)bi * HW * C_DIM;
    int c4 = lane * 4;
    float4 uv = *(const float4*)(u + (size_t)t * 256 + c4);

    float4 sv[4];
    float  part[4];
    #pragma unroll
    for (int p = 0; p < 4; p++) {
        float offw = offs[((p * 7 + h) * 7 + w) * 2 + 0];
        float offh = offs[((p * 7 + h) * 7 + w) * 2 + 1];
        float y = y1 + ((float)h + 0.5f) * bh + GAMMA * rh * offh;
        float x = x1 + ((float)w + 0.5f) * bw + GAMMA * rw * offw;
        bool valid = (y > -1.0f) && (y < (float)H_DIM) && (x > -1.0f) && (x < (float)W_DIM);
        float yc = fminf(fmaxf(y, 0.f), 127.f);
        float xc = fminf(fmaxf(x, 0.f), 127.f);
        int y0i = (int)floorf(yc);
        int x0i = (int)floorf(xc);
        int y1i = min(y0i + 1, 127);
        int x1i = min(x0i + 1, 127);
        float ly = yc - (float)y0i, lx = xc - (float)x0i;
        float hy = 1.f - ly, hx = 1.f - lx;
        float4 v00 = *(const float4*)(fb + (size_t)(y0i * W_DIM + x0i) * C_DIM + c4);
        float4 v01 = *(const float4*)(fb + (size_t)(y0i * W_DIM + x1i) * C_DIM + c4);
        float4 v10 = *(const float4*)(fb + (size_t)(y1i * W_DIM + x0i) * C_DIM + c4);
        float4 v11 = *(const float4*)(fb + (size_t)(y1i * W_DIM + x1i) * C_DIM + c4);
        float w00 = hy * hx, w01 = hy * lx, w10 = ly * hx, w11 = ly * lx;
        float4 v;
        v.x = w00 * v00.x + w01 * v01.x + w10 * v10.x + w11 * v11.x;
        v.y = w00 * v00.y + w01 * v01.y + w10 * v10.y + w11 * v11.y;
        v.z = w00 * v00.z + w01 * v01.z + w10 * v10.z + w11 * v11.z;
        v.w = w00 * v00.w + w01 * v01.w + w10 * v10.w + w11 * v11.w;
        if (!valid) { v.x = 0.f; v.y = 0.f; v.z = 0.f; v.w = 0.f; }
        sv[p] = v;
        part[p] = uv.x * v.x + uv.y * v.y + uv.z * v.z + uv.w * v.w;
    }
    #pragma unroll
    for (int mbit = 1; mbit < 64; mbit <<= 1) {
        #pragma unroll
        for (int p = 0; p < 4; p++) part[p] += __shfl_xor(part[p], mbit, 64);
    }
    float sc0 = part[0] * SCALE, sc1 = part[1] * SCALE;
    float sc2 = part[2] * SCALE, sc3 = part[3] * SCALE;
    float mx = fmaxf(fmaxf(sc0, sc1), fmaxf(sc2, sc3));
    float e0 = __expf(sc0 - mx), e1 = __expf(sc1 - mx);
    float e2 = __expf(sc2 - mx), e3 = __expf(sc3 - mx);
    float inv = 1.f / (e0 + e1 + e2 + e3);
    float4 m;
    m.x = (e0 * sv[0].x + e1 * sv[1].x + e2 * sv[2].x + e3 * sv[3].x) * inv;
    m.y = (e0 * sv[0].y + e1 * sv[1].y + e2 * sv[2].y + e3 * sv[3].y) * inv;
    m.z = (e0 * sv[0].z + e1 * sv[1].z + e2 * sv[2].z + e3 * sv[3].z) * inv;
    m.w = (e0 * sv[0].w + e1 * sv[1].w + e2 * sv[2].w + e3 * sv[3].w) * inv;
    *(float4*)(m_out + (size_t)token * 256 + c4) = m;
}

// ---------------- fallback sampler (NCHW, scalar, only if ws too small) ----------------
__global__ void sample_generic(const float* __restrict__ feat,
                               const float* __restrict__ rois,
                               const float* __restrict__ offs,
                               const float* __restrict__ u,
                               float* __restrict__ m_out,
                               int ch_stride, int pix_stride) {
    __shared__ float red[4][4];
    int token = blockIdx.x;
    int n = token / 49;
    int t = token - n * 49;
    int h = t / 7;
    int w = t - h * 7;
    const float* r = rois + (size_t)n * 5;
    int bi   = (int)r[0];
    float x1 = r[1] * SPS - 0.5f;
    float y1 = r[2] * SPS - 0.5f;
    float rw = r[3] * SPS - 0.5f - x1;
    float rh = r[4] * SPS - 0.5f - y1;
    float bw = rw * (1.0f / 7.0f);
    float bh = rh * (1.0f / 7.0f);
    int c = threadIdx.x;
    const float* fb = feat + (size_t)bi * HW * C_DIM;
    float u_c = u[(size_t)t * 256 + c];
    float sv[4], part[4];
    #pragma unroll
    for (int p = 0; p < 4; p++) {
        float offw = offs[((p * 7 + h) * 7 + w) * 2 + 0];
        float offh = offs[((p * 7 + h) * 7 + w) * 2 + 1];
        float y = y1 + ((float)h + 0.5f) * bh + GAMMA * rh * offh;
        float x = x1 + ((float)w + 0.5f) * bw + GAMMA * rw * offw;
        bool valid = (y > -1.0f) && (y < (float)H_DIM) && (x > -1.0f) && (x < (float)W_DIM);
        float yc = fminf(fmaxf(y, 0.f), 127.f);
        float xc = fminf(fmaxf(x, 0.f), 127.f);
        int y0i = (int)floorf(yc);
        int x0i = (int)floorf(xc);
        int y1i = min(y0i + 1, 127);
        int x1i = min(x0i + 1, 127);
        float ly = yc - (float)y0i, lx = xc - (float)x0i;
        float hy = 1.f - ly, hx = 1.f - lx;
        float v00 = fb[(size_t)(y0i * W_DIM + x0i) * pix_stride + (size_t)c * ch_stride];
        float v01 = fb[(size_t)(y0i * W_DIM + x1i) * pix_stride + (size_t)c * ch_stride];
        float v10 = fb[(size_t)(y1i * W_DIM + x0i) * pix_stride + (size_t)c * ch_stride];
        float v11 = fb[(size_t)(y1i * W_DIM + x1i) * pix_stride + (size_t)c * ch_stride];
        float v = hy * hx * v00 + hy * lx * v01 + ly * hx * v10 + ly * lx * v11;
        v = valid ? v : 0.f;
        sv[p] = v;
        part[p] = u_c * v;
    }
    #pragma unroll
    for (int o = 32; o >= 1; o >>= 1) {
        #pragma unroll
        for (int p = 0; p < 4; p++) part[p] += __shfl_down(part[p], o, 64);
    }
    int wv = threadIdx.x >> 6, lane = threadIdx.x & 63;
    if (lane == 0) {
        red[wv][0] = part[0]; red[wv][1] = part[1];
        red[wv][2] = part[2]; red[wv][3] = part[3];
    }
    __syncthreads();
    float sc0 = (red[0][0] + red[1][0] + red[2][0] + red[3][0]) * SCALE;
    float sc1 = (red[0][1] + red[1][1] + red[2][1] + red[3][1]) * SCALE;
    float sc2 = (red[0][2] + red[1][2] + red[2][2] + red[3][2]) * SCALE;
    float sc3 = (red[0][3] + red[1][3] + red[2][3] + red[3][3]) * SCALE;
    float mx = fmaxf(fmaxf(sc0, sc1), fmaxf(sc2, sc3));
    float e0 = __expf(sc0 - mx), e1 = __expf(sc1 - mx);
    float e2 = __expf(sc2 - mx), e3 = __expf(sc3 - mx);
    float inv = 1.f / (e0 + e1 + e2 + e3);
    m_out[(size_t)token * 256 + c] =
        (e0 * sv[0] + e1 * sv[1] + e2 * sv[2] + e3 * sv[3]) * inv;
}

// ---------------- MFMA per-roi GEMM (split-bf16, ~fp32 accuracy) ----------------
// D[t,c] = sum_d m[n,t,d] * M[c,d];  out[n,c,t] = D[t,c] + c_out[c].
// A = m rows (pad 49->64; pad rows produce garbage accs that are never stored:
// D rows are independent). B-fragment reads M[c][d] rows directly (contiguous d).
// m may alias out: all m reads complete before the first barrier.
__global__ void __launch_bounds__(256) roi_gemm_mfma(
        const float* m,
        const unsigned short* __restrict__ Mh,
        const unsigned short* __restrict__ Ml,
        const float* __restrict__ c_out,
        float* out) {
    // union: phase 1 = Ah[64][256] + Al[64][256] bf16 (65536 B)
    //        phase 2 = out-stage [256][53] fp32 (54272 B)
    __shared__ __align__(16) unsigned short lds[32768];
    unsigned short* Ah = lds;
    unsigned short* Al = lds + 64 * 256;

    int tid = threadIdx.x;
    int n = blockIdx.x;
    const float* mb = m + (size_t)n * 12544;

    // stage m -> bf16 hi/lo in LDS (float4 global reads, 8B LDS writes)
    for (int i = tid; i < 3136; i += 256) {
        float4 f = *(const float4*)(mb + (size_t)i * 4);
        us4 hi, lo;
        unsigned short h;
        h = f2bf_rne(f.x); hi.x = h; lo.x = f2bf_rne(f.x - __uint_as_float(((unsigned int)h) << 16));
        h = f2bf_rne(f.y); hi.y = h; lo.y = f2bf_rne(f.y - __uint_as_float(((unsigned int)h) << 16));
        h = f2bf_rne(f.z); hi.z = h; lo.z = f2bf_rne(f.z - __uint_as_float(((unsigned int)h) << 16));
        h = f2bf_rne(f.w); hi.w = h; lo.w = f2bf_rne(f.w - __uint_as_float(((unsigned int)h) << 16));
        int t = i >> 6;               // flat = i*4: t = flat/256
        int d = (i & 63) * 4;
        *(us4*)(Ah + t * 256 + d) = hi;
        *(us4*)(Al + t * 256 + d) = lo;
    }
    __syncthreads();

    int lane = tid & 63;
    int wave = tid >> 6;
    int col  = lane & 15;
    int quad = lane >> 4;
    int c_base = wave * 64;           // each wave: 64 columns, 64 rows

    f32x4 zero = {0.f, 0.f, 0.f, 0.f};
    f32x4 acc[4][4];                  // [rt][ct]
    #pragma unroll
    for (int i = 0; i < 4; i++)
        #pragma unroll
        for (int j = 0; j < 4; j++) acc[i][j] = zero;

    for (int ks = 0; ks < 8; ks++) {
        bf16x8 afh[4], afl[4];
        #pragma unroll
        for (int rt = 0; rt < 4; rt++) {
            int row = rt * 16 + col;
            int off = row * 256 + ks * 32 + quad * 8;
            afh[rt] = *(const bf16x8*)(Ah + off);
            afl[rt] = *(const bf16x8*)(Al + off);
        }
        #pragma unroll
        for (int ct = 0; ct < 4; ct++) {
            size_t boff = (size_t)(c_base + ct * 16 + col) * 256 + ks * 32 + quad * 8;
            bf16x8 bfh = *(const bf16x8*)(Mh + boff);
            bf16x8 bfl = *(const bf16x8*)(Ml + boff);
            #pragma unroll
            for (int rt = 0; rt < 4; rt++) {
                acc[rt][ct] = __builtin_amdgcn_mfma_f32_16x16x32_bf16(afh[rt], bfh, acc[rt][ct], 0, 0, 0);
                acc[rt][ct] = __builtin_amdgcn_mfma_f32_16x16x32_bf16(afl[rt], bfh, acc[rt][ct], 0, 0, 0);
                acc[rt][ct] = __builtin_amdgcn_mfma_f32_16x16x32_bf16(afh[rt], bfl, acc[rt][ct], 0, 0, 0);
            }
        }
    }

    __syncthreads();                  // A no longer needed; reuse LDS for epilogue
    float* ostage = (float*)lds;      // [256][53]
    #pragma unroll
    for (int rt = 0; rt < 4; rt++) {
        #pragma unroll
        for (int ct = 0; ct < 4; ct++) {
            int c = c_base + ct * 16 + col;
            float bias = c_out[c];
            #pragma unroll
            for (int r = 0; r < 4; r++) {
                int t = rt * 16 + quad * 4 + r;
                if (t < 49) ostage[c * 53 + t] = acc[rt][ct][r] + bias;
            }
        }
    }
    __syncthreads();
    float* ob = out + (size_t)n * 12544;
    for (int k = 0; k < 49; k++) {
        int flat = k * 256 + tid;     // = c2*49 + t2
        int c2 = flat / 49;
        int t2 = flat - c2 * 49;
        ob[flat] = ostage[c2 * 53 + t2];   // coalesced global store
    }
}

// ---------------- fallback fp32 GEMM (only if ws too small for NHWC path) ----------------
__global__ void __launch_bounds__(256) roi_gemm(const float* __restrict__ m,
                                                const float* __restrict__ Mtp,
                                                const float* __restrict__ c_out,
                                                float* __restrict__ out) {
    __shared__ float mlds[49 * 260];
    int c = threadIdx.x;
    int n = blockIdx.x;
    const float* mb = m + (size_t)n * 12544;
    for (int t = 0; t < 49; t++) mlds[t * 260 + c] = mb[t * 256 + c];
    __syncthreads();
    float acc[49];
    #pragma unroll
    for (int t = 0; t < 49; t++) acc[t] = 0.f;
    const float4* Mp = (const float4*)Mtp;
    for (int d4 = 0; d4 < 64; d4++) {
        float4 w4 = Mp[(size_t)d4 * 256 + c];
        #pragma unroll
        for (int t = 0; t < 49; t++) {
            float4 mv = *(const float4*)&mlds[t * 260 + d4 * 4];
            acc[t] = fmaf(w4.x, mv.x, acc[t]);
            acc[t] = fmaf(w4.y, mv.y, acc[t]);
            acc[t] = fmaf(w4.z, mv.z, acc[t]);
            acc[t] = fmaf(w4.w, mv.w, acc[t]);
        }
    }
    float bias = c_out[c];
    __syncthreads();
    #pragma unroll
    for (int t = 0; t < 49; t++) mlds[t * 260 + c] = acc[t] + bias;
    __syncthreads();
    float* ob = out + (size_t)n * 12544;
    for (int k = 0; k < 49; k++) {
        int flat = k * 256 + c;
        int c2 = flat / 49;
        int t2 = flat - c2 * 49;
        ob[flat] = mlds[t2 * 260 + c2];
    }
}

extern "C" void kernel_launch(void* const* d_in, const int* in_sizes, int n_in,
                              void* d_out, int out_size, void* d_ws, size_t ws_size,
                              hipStream_t stream) {
    (void)in_sizes; (void)n_in; (void)out_size;
    const float* features   = (const float*)d_in[0];
    const float* rois       = (const float*)d_in[1];
    const float* offs       = (const float*)d_in[2];
    const float* queries    = (const float*)d_in[3];
    const float* w_proj     = (const float*)d_in[4];
    const float* b_proj     = (const float*)d_in[5];
    const float* in_proj_w  = (const float*)d_in[6];
    const float* in_proj_b  = (const float*)d_in[7];
    const float* out_proj_w = (const float*)d_in[8];
    const float* out_proj_b = (const float*)d_in[9];
    float* out = (float*)d_out;
    float* ws  = (float*)d_ws;

    // workspace layout (floats)
    float* A_k   = ws;                    // 65536
    float* A_v   = A_k  + 65536;          // 65536
    float* Qhat  = A_v  + 65536;          // 12544
    float* cv    = Qhat + 12544;          // 256
    float* u     = cv   + 256;            // 12544
    float* c_out = u    + 12544;          // 256   -> ends at 156672
    unsigned short* Mh = (unsigned short*)(ws + 156672);  // 65536 shorts = 32768 floats
    unsigned short* Ml = (unsigned short*)(ws + 189440);  // 65536 shorts = 32768 floats
    float* feat_t = ws + 222208;          // 16777216 floats (NHWC features)
    float* Mtp    = ws + 222208;          // fallback-only: overlaps feat_t region

    size_t needT = ((size_t)222208 + (size_t)16777216) * 4;
    bool useT = ws_size >= needT;

    precompute1<<<562, 256, 0, stream>>>(w_proj, in_proj_w, in_proj_b,
                                         queries, b_proj, A_k, A_v, Qhat, cv);
    precompute2<<<306, 256, 0, stream>>>(Qhat, A_k, A_v, out_proj_w, out_proj_b,
                                         cv, u, Mh, Ml, Mtp, useT ? 0 : 1, c_out);

    float* m = out;   // alias: gemm kernels read their slice fully before writing it
    if (useT) {
        transpose_nchw_nhwc<<<dim3(256, 4, 4), 256, 0, stream>>>(features, feat_t);
        sample_nhwc<<<TOKENS / 4, 256, 0, stream>>>(feat_t, rois, offs, u, m);
        roi_gemm_mfma<<<512, 256, 0, stream>>>(m, Mh, Ml, c_out, out);
    } else {
        sample_generic<<<TOKENS, 256, 0, stream>>>(features, rois, offs, u, m, HW, 1);
        roi_gemm<<<512, 256, 0, stream>>>(m, Mtp, c_out, out);
    }
}

// Round 3
// 180.786 us; speedup vs baseline: 1.5106x; 1.1239x over previous
//
#include <hip/hip_runtime.h>
#include <math.h>

#define C_DIM 256
#define H_DIM 128
#define W_DIM 128
#define B_DIM 4
#define HW (H_DIM*W_DIM)
#define N_ROIS 512
#define OH 7
#define OW 7
#define TOKENS (N_ROIS*OH*OW)   // 25088
#define SPS 0.0625f             // spatial scale
#define GAMMA 0.1f
#define SCALE 0.0625f           // d^-0.5 = 1/16

typedef __attribute__((ext_vector_type(8))) short bf16x8;
typedef __attribute__((ext_vector_type(4))) float f32x4;
typedef __attribute__((ext_vector_type(4))) unsigned short us4;
typedef __attribute__((ext_vector_type(8))) unsigned short us8;

__device__ inline unsigned short f2bf_rne(float f) {
    unsigned int b = __float_as_uint(f);
    b += 0x7fffu + ((b >> 16) & 1u);
    return (unsigned short)(b >> 16);
}
__device__ inline float bfu(unsigned short u) {
    return __uint_as_float(((unsigned int)u) << 16);
}

// ---------------- precompute 1: A_k = Wk@W_proj, A_v = Wv@W_proj,
//                  Qhat = queries@Wq.T + bq, cv = Wv@b_proj + bv ----------------
__global__ void precompute1(const float* __restrict__ w_proj,
                            const float* __restrict__ in_proj_w,
                            const float* __restrict__ in_proj_b,
                            const float* __restrict__ queries,
                            const float* __restrict__ b_proj,
                            float* __restrict__ A_k, float* __restrict__ A_v,
                            float* __restrict__ Qhat, float* __restrict__ cv) {
    int idx = blockIdx.x * 256 + threadIdx.x;
    if (idx < 65536) {                       // A_k[i,j]
        int i = idx >> 8, j = idx & 255;
        const float* wk = in_proj_w + (size_t)(256 + i) * 256;
        float s = 0.f;
        for (int t = 0; t < 256; t++) s += wk[t] * w_proj[t * 256 + j];
        A_k[idx] = s;
    } else if (idx < 131072) {               // A_v[i,j]
        int e = idx - 65536;
        int i = e >> 8, j = e & 255;
        const float* wv = in_proj_w + (size_t)(512 + i) * 256;
        float s = 0.f;
        for (int t = 0; t < 256; t++) s += wv[t] * w_proj[t * 256 + j];
        A_v[e] = s;
    } else if (idx < 143616) {               // Qhat[s,i]
        int e = idx - 131072;
        int s_ = e >> 8, i = e & 255;
        const float* q  = queries + (size_t)s_ * 256;
        const float* wq = in_proj_w + (size_t)i * 256;
        float s = in_proj_b[i];
        for (int t = 0; t < 256; t++) s += q[t] * wq[t];
        Qhat[e] = s;
    } else {                                 // cv[i]
        int i = idx - 143616;
        const float* wv = in_proj_w + (size_t)(512 + i) * 256;
        float s = in_proj_b[512 + i];
        for (int t = 0; t < 256; t++) s += wv[t] * b_proj[t];
        cv[i] = s;
    }
}

// ---------------- precompute 2: u = Qhat@A_k, M = W_o@A_v (bf16 hi/lo split,
//                  natural [c][d] layout = MFMA B-fragment friendly),
//                  optionally fp32 packed Mtp for the fallback path,
//                  c_out = W_o@cv + b_o ----------------
__global__ void precompute2(const float* __restrict__ Qhat,
                            const float* __restrict__ A_k,
                            const float* __restrict__ A_v,
                            const float* __restrict__ out_proj_w,
                            const float* __restrict__ out_proj_b,
                            const float* __restrict__ cv,
                            float* __restrict__ u,
                            unsigned short* __restrict__ Mh,
                            unsigned short* __restrict__ Ml,
                            float* __restrict__ Mtp, int writeMtp,
                            float* __restrict__ c_out) {
    int idx = blockIdx.x * 256 + threadIdx.x;
    if (idx < 12544) {                       // u[s,j]
        int s_ = idx >> 8, j = idx & 255;
        const float* qh = Qhat + (size_t)s_ * 256;
        float s = 0.f;
        for (int i = 0; i < 256; i++) s += qh[i] * A_k[i * 256 + j];
        u[idx] = s;
    } else if (idx < 78080) {                // M[c,d], lanes vary d -> coalesced
        int e = idx - 12544;
        int c = e >> 8, d = e & 255;
        const float* wo = out_proj_w + (size_t)c * 256;
        float s = 0.f;
        for (int i = 0; i < 256; i++) s += wo[i] * A_v[i * 256 + d];
        unsigned short hi = f2bf_rne(s);
        float fh = bfu(hi);
        unsigned short lo = f2bf_rne(s - fh);
        Mh[(size_t)c * 256 + d] = hi;
        Ml[(size_t)c * 256 + d] = lo;
        if (writeMtp)
            Mtp[((size_t)(d >> 2) * 256 + c) * 4 + (d & 3)] = s;
    } else {                                 // c_out[c]
        int c = idx - 78080;
        const float* wo = out_proj_w + (size_t)c * 256;
        float s = out_proj_b[c];
        for (int i = 0; i < 256; i++) s += wo[i] * cv[i];
        c_out[c] = s;
    }
}

// ---------------- NCHW fp32 -> NHWC bf16 transpose of features ----------------
__global__ void transpose_bf16(const float* __restrict__ f,
                               unsigned short* __restrict__ ft) {
    __shared__ float tile[64][65];
    int b  = blockIdx.z;
    int c0 = blockIdx.y * 64;
    int s0 = blockIdx.x * 64;
    const float* fin = f + (size_t)b * C_DIM * HW;
    int sl = threadIdx.x & 63, cw = threadIdx.x >> 6;
    #pragma unroll
    for (int k = 0; k < 16; k++) {
        int cl = cw + k * 4;
        tile[cl][sl] = fin[(size_t)(c0 + cl) * HW + s0 + sl];
    }
    __syncthreads();
    unsigned short* fo = ft + (size_t)b * HW * C_DIM;
    int cl = threadIdx.x & 63, sw = threadIdx.x >> 6;
    #pragma unroll
    for (int k = 0; k < 16; k++) {
        int sl2 = sw + k * 4;
        fo[(size_t)(s0 + sl2) * C_DIM + c0 + cl] = f2bf_rne(tile[cl][sl2]);
    }
}

// ---------------- fused: sample + softmax-mix -> LDS bf16 A-tile -> MFMA GEMM ----------------
// One block per roi. Phase A: 8 half-waves each sample tokens t, t+8, ...
// (32 lanes x 8 channels, bf16x8 corner loads from NHWC bf16 features),
// online softmax over the 4 deform points, mixed value -> bf16 into LDS A.
// Phase B: D[t,c] = sum_d A[t,d]*M[c,d] via 16x16x32 bf16 MFMA (B split hi/lo),
// epilogue restaged through LDS for coalesced out[n,c,t] stores.
__global__ void __launch_bounds__(256) fused_sample_gemm(
        const unsigned short* __restrict__ feat_b,
        const float* __restrict__ rois,
        const float* __restrict__ offs,
        const float* __restrict__ u,
        const unsigned short* __restrict__ Mh,
        const unsigned short* __restrict__ Ml,
        const float* __restrict__ c_out,
        float* __restrict__ out) {
    // union: phase A/B = A[64][264] bf16 (33792 B, stride 264 kills the
    // 512B-row bank aliasing on a-fragment ds_read_b128);
    // epilogue = ostage[256][53] fp32 (54272 B)
    __shared__ __align__(16) char ldsraw[54272];
    unsigned short* A = (unsigned short*)ldsraw;

    int tid = threadIdx.x;
    int n = blockIdx.x;

    const float* r = rois + (size_t)n * 5;
    int bi   = (int)r[0];
    float x1 = r[1] * SPS - 0.5f;
    float y1v = r[2] * SPS - 0.5f;
    float rw = r[3] * SPS - 0.5f - x1;
    float rh = r[4] * SPS - 0.5f - y1v;
    float bw = rw * (1.0f / 7.0f);
    float bh = rh * (1.0f / 7.0f);
    const unsigned short* fb = feat_b + (size_t)bi * HW * C_DIM;

    int lane32 = tid & 31;
    int halfw  = tid >> 5;
    int c8 = lane32 * 8;

    for (int t = halfw; t < 49; t += 8) {
        int hb = t / 7, wb = t - hb * 7;
        const float* up = u + (size_t)t * 256 + c8;
        float uu[8];
        *(float4*)uu       = *(const float4*)up;
        *(float4*)(uu + 4) = *(const float4*)(up + 4);

        float sv[4][8];
        float part[4];
        #pragma unroll
        for (int p = 0; p < 4; p++) {
            float offw = offs[((p * 7 + hb) * 7 + wb) * 2 + 0];
            float offh = offs[((p * 7 + hb) * 7 + wb) * 2 + 1];
            float y = y1v + ((float)hb + 0.5f) * bh + GAMMA * rh * offh;
            float x = x1  + ((float)wb + 0.5f) * bw + GAMMA * rw * offw;
            bool valid = (y > -1.0f) && (y < 128.0f) && (x > -1.0f) && (x < 128.0f);
            float yc = fminf(fmaxf(y, 0.f), 127.f);
            float xc = fminf(fmaxf(x, 0.f), 127.f);
            int y0i = (int)yc, x0i = (int)xc;       // >=0: trunc == floor
            int y1i = min(y0i + 1, 127), x1i = min(x0i + 1, 127);
            float ly = yc - (float)y0i, lx = xc - (float)x0i;
            float hy = 1.f - ly, hx = 1.f - lx;
            float w00 = hy * hx, w01 = hy * lx, w10 = ly * hx, w11 = ly * lx;
            if (!valid) { w00 = 0.f; w01 = 0.f; w10 = 0.f; w11 = 0.f; }
            us8 r00 = *(const us8*)(fb + (size_t)(y0i * W_DIM + x0i) * C_DIM + c8);
            us8 r01 = *(const us8*)(fb + (size_t)(y0i * W_DIM + x1i) * C_DIM + c8);
            us8 r10 = *(const us8*)(fb + (size_t)(y1i * W_DIM + x0i) * C_DIM + c8);
            us8 r11 = *(const us8*)(fb + (size_t)(y1i * W_DIM + x1i) * C_DIM + c8);
            float accp = 0.f;
            #pragma unroll
            for (int j = 0; j < 8; j++) {
                float v = w00 * bfu(r00[j]) + w01 * bfu(r01[j])
                        + w10 * bfu(r10[j]) + w11 * bfu(r11[j]);
                sv[p][j] = v;
                accp = fmaf(uu[j], v, accp);
            }
            part[p] = accp;
        }
        // reduce the 4 dot products over the 32-lane group (xor masks stay in-half)
        #pragma unroll
        for (int mk = 1; mk <= 16; mk <<= 1) {
            #pragma unroll
            for (int p = 0; p < 4; p++) part[p] += __shfl_xor(part[p], mk, 64);
        }
        float sc0 = part[0] * SCALE, sc1 = part[1] * SCALE;
        float sc2 = part[2] * SCALE, sc3 = part[3] * SCALE;
        float mx = fmaxf(fmaxf(sc0, sc1), fmaxf(sc2, sc3));
        float e0 = __expf(sc0 - mx), e1 = __expf(sc1 - mx);
        float e2 = __expf(sc2 - mx), e3 = __expf(sc3 - mx);
        float inv = 1.f / (e0 + e1 + e2 + e3);
        us8 o8;
        #pragma unroll
        for (int j = 0; j < 8; j++) {
            float mv = (e0 * sv[0][j] + e1 * sv[1][j]
                      + e2 * sv[2][j] + e3 * sv[3][j]) * inv;
            o8[j] = f2bf_rne(mv);
        }
        *(us8*)(A + t * 264 + c8) = o8;
    }
    // zero pad rows 49..63 (their D rows are computed but never stored)
    for (int i = tid; i < 480; i += 256) {
        int row = 49 + (i >> 5);
        int cs = (i & 31) * 8;
        us8 z = {0, 0, 0, 0, 0, 0, 0, 0};
        *(us8*)(A + row * 264 + cs) = z;
    }
    __syncthreads();

    int lane = tid & 63;
    int wave = tid >> 6;
    int col  = lane & 15;
    int quad = lane >> 4;
    int cbase = wave * 64;            // each wave: 64 out-channels x 64 rows

    f32x4 zero = {0.f, 0.f, 0.f, 0.f};
    f32x4 acc[4][4];                  // [rt][ct]
    #pragma unroll
    for (int i = 0; i < 4; i++)
        #pragma unroll
        for (int j = 0; j < 4; j++) acc[i][j] = zero;

    for (int ks = 0; ks < 8; ks++) {
        bf16x8 af[4];
        #pragma unroll
        for (int rt = 0; rt < 4; rt++)
            af[rt] = *(const bf16x8*)(A + (rt * 16 + col) * 264 + ks * 32 + quad * 8);
        #pragma unroll
        for (int ct = 0; ct < 4; ct++) {
            size_t bo = (size_t)(cbase + ct * 16 + col) * 256 + ks * 32 + quad * 8;
            bf16x8 bh8 = *(const bf16x8*)(Mh + bo);
            bf16x8 bl8 = *(const bf16x8*)(Ml + bo);
            #pragma unroll
            for (int rt = 0; rt < 4; rt++) {
                acc[rt][ct] = __builtin_amdgcn_mfma_f32_16x16x32_bf16(af[rt], bh8, acc[rt][ct], 0, 0, 0);
                acc[rt][ct] = __builtin_amdgcn_mfma_f32_16x16x32_bf16(af[rt], bl8, acc[rt][ct], 0, 0, 0);
            }
        }
    }

    __syncthreads();                  // A no longer needed; reuse LDS for epilogue
    float* ostage = (float*)ldsraw;   // [256][53]
    #pragma unroll
    for (int rt = 0; rt < 4; rt++) {
        #pragma unroll
        for (int ct = 0; ct < 4; ct++) {
            int c = cbase + ct * 16 + col;
            float bias = c_out[c];
            #pragma unroll
            for (int rr = 0; rr < 4; rr++) {
                int t = rt * 16 + quad * 4 + rr;
                if (t < 49) ostage[c * 53 + t] = acc[rt][ct][rr] + bias;
            }
        }
    }
    __syncthreads();
    float* ob = out + (size_t)n * 12544;
    for (int k = 0; k < 49; k++) {
        int flat = k * 256 + tid;     // = c2*49 + t2
        int c2 = flat / 49;
        int t2 = flat - c2 * 49;
        ob[flat] = ostage[c2 * 53 + t2];   // coalesced global store
    }
}

// ---------------- fallback sampler (NCHW, scalar, only if ws too small) ----------------
__global__ void sample_generic(const float* __restrict__ feat,
                               const float* __restrict__ rois,
                               const float* __restrict__ offs,
                               const float* __restrict__ u,
                               float* __restrict__ m_out,
                               int ch_stride, int pix_stride) {
    __shared__ float red[4][4];
    int token = blockIdx.x;
    int n = token / 49;
    int t = token - n * 49;
    int h = t / 7;
    int w = t - h * 7;
    const float* r = rois + (size_t)n * 5;
    int bi   = (int)r[0];
    float x1 = r[1] * SPS - 0.5f;
    float y1 = r[2] * SPS - 0.5f;
    float rw = r[3] * SPS - 0.5f - x1;
    float rh = r[4] * SPS - 0.5f - y1;
    float bw = rw * (1.0f / 7.0f);
    float bh = rh * (1.0f / 7.0f);
    int c = threadIdx.x;
    const float* fb = feat + (size_t)bi * HW * C_DIM;
    float u_c = u[(size_t)t * 256 + c];
    float sv[4], part[4];
    #pragma unroll
    for (int p = 0; p < 4; p++) {
        float offw = offs[((p * 7 + h) * 7 + w) * 2 + 0];
        float offh = offs[((p * 7 + h) * 7 + w) * 2 + 1];
        float y = y1 + ((float)h + 0.5f) * bh + GAMMA * rh * offh;
        float x = x1 + ((float)w + 0.5f) * bw + GAMMA * rw * offw;
        bool valid = (y > -1.0f) && (y < (float)H_DIM) && (x > -1.0f) && (x < (float)W_DIM);
        float yc = fminf(fmaxf(y, 0.f), 127.f);
        float xc = fminf(fmaxf(x, 0.f), 127.f);
        int y0i = (int)floorf(yc);
        int x0i = (int)floorf(xc);
        int y1i = min(y0i + 1, 127);
        int x1i = min(x0i + 1, 127);
        float ly = yc - (float)y0i, lx = xc - (float)x0i;
        float hy = 1.f - ly, hx = 1.f - lx;
        float v00 = fb[(size_t)(y0i * W_DIM + x0i) * pix_stride + (size_t)c * ch_stride];
        float v01 = fb[(size_t)(y0i * W_DIM + x1i) * pix_stride + (size_t)c * ch_stride];
        float v10 = fb[(size_t)(y1i * W_DIM + x0i) * pix_stride + (size_t)c * ch_stride];
        float v11 = fb[(size_t)(y1i * W_DIM + x1i) * pix_stride + (size_t)c * ch_stride];
        float v = hy * hx * v00 + hy * lx * v01 + ly * hx * v10 + ly * lx * v11;
        v = valid ? v : 0.f;
        sv[p] = v;
        part[p] = u_c * v;
    }
    #pragma unroll
    for (int o = 32; o >= 1; o >>= 1) {
        #pragma unroll
        for (int p = 0; p < 4; p++) part[p] += __shfl_down(part[p], o, 64);
    }
    int wv = threadIdx.x >> 6, lane = threadIdx.x & 63;
    if (lane == 0) {
        red[wv][0] = part[0]; red[wv][1] = part[1];
        red[wv][2] = part[2]; red[wv][3] = part[3];
    }
    __syncthreads();
    float sc0 = (red[0][0] + red[1][0] + red[2][0] + red[3][0]) * SCALE;
    float sc1 = (red[0][1] + red[1][1] + red[2][1] + red[3][1]) * SCALE;
    float sc2 = (red[0][2] + red[1][2] + red[2][2] + red[3][2]) * SCALE;
    float sc3 = (red[0][3] + red[1][3] + red[2][3] + red[3][3]) * SCALE;
    float mx = fmaxf(fmaxf(sc0, sc1), fmaxf(sc2, sc3));
    float e0 = __expf(sc0 - mx), e1 = __expf(sc1 - mx);
    float e2 = __expf(sc2 - mx), e3 = __expf(sc3 - mx);
    float inv = 1.f / (e0 + e1 + e2 + e3);
    m_out[(size_t)token * 256 + c] =
        (e0 * sv[0] + e1 * sv[1] + e2 * sv[2] + e3 * sv[3]) * inv;
}

// ---------------- fallback fp32 GEMM (only if ws too small) ----------------
__global__ void __launch_bounds__(256) roi_gemm(const float* __restrict__ m,
                                                const float* __restrict__ Mtp,
                                                const float* __restrict__ c_out,
                                                float* __restrict__ out) {
    __shared__ float mlds[49 * 260];
    int c = threadIdx.x;
    int n = blockIdx.x;
    const float* mb = m + (size_t)n * 12544;
    for (int t = 0; t < 49; t++) mlds[t * 260 + c] = mb[t * 256 + c];
    __syncthreads();
    float acc[49];
    #pragma unroll
    for (int t = 0; t < 49; t++) acc[t] = 0.f;
    const float4* Mp = (const float4*)Mtp;
    for (int d4 = 0; d4 < 64; d4++) {
        float4 w4 = Mp[(size_t)d4 * 256 + c];
        #pragma unroll
        for (int t = 0; t < 49; t++) {
            float4 mv = *(const float4*)&mlds[t * 260 + d4 * 4];
            acc[t] = fmaf(w4.x, mv.x, acc[t]);
            acc[t] = fmaf(w4.y, mv.y, acc[t]);
            acc[t] = fmaf(w4.z, mv.z, acc[t]);
            acc[t] = fmaf(w4.w, mv.w, acc[t]);
        }
    }
    float bias = c_out[c];
    __syncthreads();
    #pragma unroll
    for (int t = 0; t < 49; t++) mlds[t * 260 + c] = acc[t] + bias;
    __syncthreads();
    float* ob = out + (size_t)n * 12544;
    for (int k = 0; k < 49; k++) {
        int flat = k * 256 + c;
        int c2 = flat / 49;
        int t2 = flat - c2 * 49;
        ob[flat] = mlds[t2 * 260 + c2];
    }
}

extern "C" void kernel_launch(void* const* d_in, const int* in_sizes, int n_in,
                              void* d_out, int out_size, void* d_ws, size_t ws_size,
                              hipStream_t stream) {
    (void)in_sizes; (void)n_in; (void)out_size;
    const float* features   = (const float*)d_in[0];
    const float* rois       = (const float*)d_in[1];
    const float* offs       = (const float*)d_in[2];
    const float* queries    = (const float*)d_in[3];
    const float* w_proj     = (const float*)d_in[4];
    const float* b_proj     = (const float*)d_in[5];
    const float* in_proj_w  = (const float*)d_in[6];
    const float* in_proj_b  = (const float*)d_in[7];
    const float* out_proj_w = (const float*)d_in[8];
    const float* out_proj_b = (const float*)d_in[9];
    float* out = (float*)d_out;
    float* ws  = (float*)d_ws;

    // workspace layout (float units)
    float* A_k   = ws;                    // 65536
    float* A_v   = A_k  + 65536;          // 65536
    float* Qhat  = A_v  + 65536;          // 12544
    float* cv    = Qhat + 12544;          // 256
    float* u     = cv   + 256;            // 12544
    float* c_out = u    + 12544;          // 256   -> ends at 156672
    unsigned short* Mh = (unsigned short*)(ws + 156672);  // 65536 shorts
    unsigned short* Ml = (unsigned short*)(ws + 189440);  // 65536 shorts
    unsigned short* feat_b = (unsigned short*)(ws + 222208); // 16777216 shorts (NHWC bf16)
    float* Mtp    = ws + 222208;          // fallback-only: overlaps feat_b region
    float* m_fb   = ws + 222208 + 65536;  // fallback m buffer (25088*256 floats)

    size_t needT = ((size_t)222208 + (size_t)8388608) * 4;
    size_t needF = ((size_t)222208 + (size_t)65536 + (size_t)TOKENS * 256) * 4;
    bool useT = ws_size >= needT;

    precompute1<<<562, 256, 0, stream>>>(w_proj, in_proj_w, in_proj_b,
                                         queries, b_proj, A_k, A_v, Qhat, cv);
    precompute2<<<306, 256, 0, stream>>>(Qhat, A_k, A_v, out_proj_w, out_proj_b,
                                         cv, u, Mh, Ml, Mtp, useT ? 0 : 1, c_out);

    if (useT) {
        transpose_bf16<<<dim3(256, 4, 4), 256, 0, stream>>>(features, feat_b);
        fused_sample_gemm<<<N_ROIS, 256, 0, stream>>>(feat_b, rois, offs, u,
                                                      Mh, Ml, c_out, out);
    } else {
        float* m = (ws_size >= needF) ? m_fb : out;  // alias out only as last resort
        sample_generic<<<TOKENS, 256, 0, stream>>>(features, rois, offs, u, m, HW, 1);
        roi_gemm<<<512, 256, 0, stream>>>(m, Mtp, c_out, out);
    }
}